// Round 9
// baseline (158.104 us; speedup 1.0000x reference)
//
#include <hip/hip_runtime.h>

#define NN 100000
#define NE 1600000
#define DIN 128
#define DOUT 32
#define NBUK 391     // ceil(NN/256) buckets of 256 nodes
#define FILLB 196    // edge chunks
#define CHUNK 8192   // edges per chunk (196*8192 >= NE)
#define CAP 8192     // max records per bucket staged in LDS (mean 4092, sd ~64)

typedef unsigned short ushort_t;
typedef unsigned int uint_t;
typedef _Float16 f16x8 __attribute__((ext_vector_type(8)));
typedef _Float16 f16x2 __attribute__((ext_vector_type(2)));
typedef float f32x4 __attribute__((ext_vector_type(4)));

static __device__ __forceinline__ ushort_t f2h_u(float f) {
    _Float16 h = (_Float16)f;
    ushort_t u;
    __builtin_memcpy(&u, &h, 2);
    return u;
}
static __device__ __forceinline__ f16x2 u2h2(uint_t u) {
    f16x2 h;
    __builtin_memcpy(&h, &u, 4);
    return h;
}

// ===========================================================================
// k1: per-(chunk,bucket) histogram -> histmat[FILLB][NBUK]. LDS atomics only.
// ===========================================================================
__global__ __launch_bounds__(256)
void hist_kernel(const int* __restrict__ col, int* __restrict__ histmat) {
    __shared__ int h[NBUK];
    int t = threadIdx.x, blk = blockIdx.x;
    for (int b = t; b < NBUK; b += 256) h[b] = 0;
    __syncthreads();
    int e0 = blk * CHUNK, emax = min(e0 + CHUNK, NE);
    for (int e = e0 + t; e < emax; e += 256) atomicAdd(&h[col[e] >> 8], 1);
    __syncthreads();
    for (int b = t; b < NBUK; b += 256) histmat[(size_t)blk * NBUK + b] = h[b];
}

// ===========================================================================
// k2a: per-bucket exclusive scan over the 196 chunks (in place) + bucket totals
// ===========================================================================
__global__ __launch_bounds__(256)
void colscan_kernel(int* __restrict__ histmat, int* __restrict__ bsum) {
    __shared__ int s[256];
    int b = blockIdx.x, t = threadIdx.x;
    int v = (t < FILLB) ? histmat[(size_t)t * NBUK + b] : 0;
    s[t] = v;
    __syncthreads();
    for (int off = 1; off < 256; off <<= 1) {
        int u = (t >= off) ? s[t - off] : 0;
        __syncthreads();
        s[t] += u;
        __syncthreads();
    }
    if (t < FILLB) histmat[(size_t)t * NBUK + b] = s[t] - v;  // exclusive
    if (t == FILLB - 1) bsum[b] = s[t];
}

// ===========================================================================
// k2b: block 0: exclusive scan of bucket totals -> base[NBUK+1]
//      blocks 1..8: Wht[c][k] = f16(W[k][c])  (transposed fp16 weights, 8 KB)
// ===========================================================================
__global__ __launch_bounds__(512)
void bscan_wb_kernel(const int* __restrict__ bsum, int* __restrict__ base,
                     const float* __restrict__ W, ushort_t* __restrict__ Wht) {
    if (blockIdx.x == 0) {
        __shared__ int s[512];
        int t = threadIdx.x;
        int own = (t < NBUK) ? bsum[t] : 0;
        s[t] = own;
        __syncthreads();
        for (int off = 1; off < 512; off <<= 1) {
            int v = (t >= off) ? s[t - off] : 0;
            __syncthreads();
            s[t] += v;
            __syncthreads();
        }
        if (t < NBUK) {
            base[t] = s[t] - own;
            if (t == NBUK - 1) base[NBUK] = s[t];
        }
    } else {
        int i = (blockIdx.x - 1) * 512 + threadIdx.x;
        if (i < DIN * DOUT) {
            int c = i >> 7;       // 0..31
            int k = i & 127;      // 0..127
            Wht[(size_t)c * DIN + k] = f2h_u(W[(size_t)k * DOUT + c]);
        }
    }
}

// ===========================================================================
// k3: fill records at deterministic positions (LDS cursors, no global atomics)
// record = (row << 8) | (col & 255)
// ===========================================================================
__global__ __launch_bounds__(256)
void fill_kernel(const int* __restrict__ row, const int* __restrict__ col,
                 const int* __restrict__ base, const int* __restrict__ histmat,
                 unsigned int* __restrict__ records) {
    __shared__ int lcur[NBUK];
    int t = threadIdx.x, blk = blockIdx.x;
    for (int b = t; b < NBUK; b += 256)
        lcur[b] = base[b] + histmat[(size_t)blk * NBUK + b];
    __syncthreads();
    int e0 = blk * CHUNK, emax = min(e0 + CHUNK, NE);
    for (int e = e0 + t; e < emax; e += 256) {
        int c = col[e];
        int slot = atomicAdd(&lcur[c >> 8], 1);
        records[slot] = ((unsigned int)row[e] << 8) | (unsigned int)(c & 255);
    }
}

// ===========================================================================
// k4: per-bucket sort (records -> grouped by node, in place), + deg -> dis,
// + per-node CSR offsets. All writes block-local / coalesced.
// ===========================================================================
__global__ __launch_bounds__(256)
void sort_kernel(const int* __restrict__ base, unsigned int* __restrict__ records,
                 float* __restrict__ dis, int* __restrict__ offs) {
    __shared__ unsigned int stage[CAP];  // 32 KB
    __shared__ int hist[256];
    __shared__ int sc[256];
    __shared__ int lcur[256];
    int b = blockIdx.x, t = threadIdx.x;
    int s = base[b], e = base[b + 1];
    int cnt = e - s;
    hist[t] = 0;
    for (int j = t; j < cnt; j += 256) stage[j] = records[s + j];
    __syncthreads();
    for (int j = t; j < cnt; j += 256) atomicAdd(&hist[stage[j] & 255u], 1);
    __syncthreads();
    int d = hist[t];
    sc[t] = d;
    __syncthreads();
    for (int off = 1; off < 256; off <<= 1) {
        int u = (t >= off) ? sc[t - off] : 0;
        __syncthreads();
        sc[t] += u;
        __syncthreads();
    }
    int excl = sc[t] - d;
    int n = (b << 8) + t;
    if (n < NN) {
        dis[n] = rsqrtf((float)(d + 1));
        offs[n] = s + excl;
        if (n == NN - 1) offs[NN] = e;
    }
    lcur[t] = excl;
    __syncthreads();
    for (int j = t; j < cnt; j += 256) {
        unsigned int rec = stage[j];
        int slot = atomicAdd(&lcur[rec & 255u], 1);
        records[s + slot] = rec >> 8;  // now plain src row id
    }
}

// ===========================================================================
// k5: (x @ W) * dis -> two f16 half-arrays xwl/xwh = [NN][16] (3.2 MB each,
// XCD-L2-resident for the aggregate passes). MFMA 16x16x32_f16, one wave = 16
// rows, 6250 waves.
// ===========================================================================
__global__ __launch_bounds__(256)
void xw_kernel(const float* __restrict__ x, const ushort_t* __restrict__ Wht,
               const float* __restrict__ dis,
               ushort_t* __restrict__ xwl, ushort_t* __restrict__ xwh) {
    int t = threadIdx.x;
    int wv = t >> 6, lane = t & 63;
    int wtile = blockIdx.x * 4 + wv;
    if (wtile >= NN / 16) return;          // uniform per wave
    int r0 = wtile * 16;
    int rowi = lane & 15;                  // A-row / B-col / D-col
    int kg = lane >> 4;                    // k-group (0..3)

    // B fragments: 2 N-tiles x 4 K-steps, 16B each from Wht
    f16x8 bfrag[2][4];
#pragma unroll
    for (int t2 = 0; t2 < 2; ++t2)
#pragma unroll
        for (int s = 0; s < 4; ++s)
            bfrag[t2][s] = *(const f16x8*)(Wht + (size_t)(t2 * 16 + rowi) * DIN + s * 32 + kg * 8);

    // A: row r0+rowi, 8 fp32 per K-step at k = s*32 + kg*8
    const float* __restrict__ xr = x + (size_t)(r0 + rowi) * DIN;
    float4 xa[8];
#pragma unroll
    for (int s = 0; s < 4; ++s) {
        xa[2 * s]     = *(const float4*)(xr + s * 32 + kg * 8);
        xa[2 * s + 1] = *(const float4*)(xr + s * 32 + kg * 8 + 4);
    }
    f16x8 afrag[4];
#pragma unroll
    for (int s = 0; s < 4; ++s) {
        f16x8 a;
        a[0] = (_Float16)xa[2 * s].x;     a[1] = (_Float16)xa[2 * s].y;
        a[2] = (_Float16)xa[2 * s].z;     a[3] = (_Float16)xa[2 * s].w;
        a[4] = (_Float16)xa[2 * s + 1].x; a[5] = (_Float16)xa[2 * s + 1].y;
        a[6] = (_Float16)xa[2 * s + 1].z; a[7] = (_Float16)xa[2 * s + 1].w;
        afrag[s] = a;
    }

    f32x4 acc0 = {0.f, 0.f, 0.f, 0.f};
    f32x4 acc1 = {0.f, 0.f, 0.f, 0.f};
#pragma unroll
    for (int s = 0; s < 4; ++s) {
        acc0 = __builtin_amdgcn_mfma_f32_16x16x32_f16(afrag[s], bfrag[0][s], acc0, 0, 0, 0);
        acc1 = __builtin_amdgcn_mfma_f32_16x16x32_f16(afrag[s], bfrag[1][s], acc1, 0, 0, 0);
    }

    // D[row = kg*4+j][col = rowi]; scale by dis[row]; cols 0-15 -> xwl, 16-31 -> xwh
#pragma unroll
    for (int j = 0; j < 4; ++j) {
        int orow = r0 + kg * 4 + j;
        float dv = dis[orow];
        xwl[(size_t)orow * 16 + rowi] = f2h_u(acc0[j] * dv);
        xwh[(size_t)orow * 16 + rowi] = f2h_u(acc1[j] * dv);
    }
}

// ===========================================================================
// k6: per-node wave gather over one 16-dim f16 half (32 B/edge from a 3.2 MB
// L2-resident array). lane = (slot 0..31, dh 0..1): 32 edges/iter; packed
// v_pk_add_f16 accumulation in the loop (1-2 adds deep), f32 tree reduce.
// ===========================================================================
__global__ __launch_bounds__(256)
void aggregate_half_kernel(const int* __restrict__ offs, const int* __restrict__ srcs,
                           const float* __restrict__ dis, const ushort_t* __restrict__ xwp,
                           const float* __restrict__ bias, float* __restrict__ out,
                           int halfsel) {
    int wid = (int)((blockIdx.x * blockDim.x + threadIdx.x) >> 6);
    if (wid >= NN) return;
    int lane = threadIdx.x & 63;
    int slot = lane >> 1;        // 0..31 edge slot
    int dh = lane & 1;           // 8-dim sub-half: dims dh*8 .. dh*8+7 (of 16)
    int s = offs[wid], e = offs[wid + 1];
    f16x2 acc[4] = {{(_Float16)0.f, (_Float16)0.f}, {(_Float16)0.f, (_Float16)0.f},
                    {(_Float16)0.f, (_Float16)0.f}, {(_Float16)0.f, (_Float16)0.f}};
#pragma unroll 2
    for (int i = s; i < e; i += 32) {
        int j = i + slot;
        bool ok = j < e;
        int r = srcs[ok ? j : e - 1];
        uint4 u = *(const uint4*)(xwp + (size_t)r * 16 + dh * 8);
        if (!ok) { u.x = 0u; u.y = 0u; u.z = 0u; u.w = 0u; }
        acc[0] += u2h2(u.x);
        acc[1] += u2h2(u.y);
        acc[2] += u2h2(u.z);
        acc[3] += u2h2(u.w);
    }
    // unpack to f32, tree-reduce over 32 slots
    float a[8];
#pragma unroll
    for (int k = 0; k < 4; ++k) {
        a[2 * k]     = (float)acc[k][0];
        a[2 * k + 1] = (float)acc[k][1];
    }
#pragma unroll
    for (int msk = 2; msk <= 32; msk <<= 1) {
#pragma unroll
        for (int v = 0; v < 8; ++v) a[v] += __shfl_xor(a[v], msk, 64);
    }
    if (slot == 0) {
        uint4 su = *(const uint4*)(xwp + (size_t)wid * 16 + dh * 8);  // self-loop
        f16x2 s0 = u2h2(su.x), s1 = u2h2(su.y), s2 = u2h2(su.z), s3 = u2h2(su.w);
        a[0] += (float)s0[0]; a[1] += (float)s0[1];
        a[2] += (float)s1[0]; a[3] += (float)s1[1];
        a[4] += (float)s2[0]; a[5] += (float)s2[1];
        a[6] += (float)s3[0]; a[7] += (float)s3[1];
        float dc = dis[wid];
        int dbase = halfsel * 16 + dh * 8;
        float4 b0 = *(const float4*)(bias + dbase);
        float4 b1 = *(const float4*)(bias + dbase + 4);
        float4 o0, o1;
        o0.x = dc * a[0] + b0.x; o0.y = dc * a[1] + b0.y;
        o0.z = dc * a[2] + b0.z; o0.w = dc * a[3] + b0.w;
        o1.x = dc * a[4] + b1.x; o1.y = dc * a[5] + b1.y;
        o1.z = dc * a[6] + b1.z; o1.w = dc * a[7] + b1.w;
        *(float4*)(out + (size_t)wid * DOUT + dbase) = o0;
        *(float4*)(out + (size_t)wid * DOUT + dbase + 4) = o1;
    }
}

// ===========================================================================
// Fallback path (R1) if workspace is too small
// ===========================================================================
__global__ void deg_count_kernel(const int* __restrict__ col, int* __restrict__ deg) {
    int e = blockIdx.x * blockDim.x + threadIdx.x;
    if (e < NE) atomicAdd(&deg[col[e]], 1);
}
__global__ void dis_kernel(const int* __restrict__ deg, float* __restrict__ dis) {
    int i = blockIdx.x * blockDim.x + threadIdx.x;
    if (i < NN) dis[i] = rsqrtf((float)(deg[i] + 1));
}
__global__ void xw_init_kernel(const float* __restrict__ x, const float* __restrict__ W,
                               const float* __restrict__ b, const float* __restrict__ dis,
                               float* __restrict__ xw, float* __restrict__ out) {
    __shared__ float Ws[DIN * DOUT];
    for (int i = threadIdx.x; i < DIN * DOUT; i += blockDim.x) Ws[i] = W[i];
    __syncthreads();
    int idx = blockIdx.x * blockDim.x + threadIdx.x;
    if (idx >= NN * DOUT) return;
    int n = idx >> 5;
    int d = idx & (DOUT - 1);
    const float* xr = x + (long long)n * DIN;
    float acc = 0.f;
#pragma unroll
    for (int k = 0; k < DIN; ++k) acc += xr[k] * Ws[k * DOUT + d];
    xw[idx] = acc;
    float di = dis[n];
    out[idx] = di * di * acc + b[d];
}
__global__ void scatter_kernel(const int* __restrict__ row, const int* __restrict__ col,
                               const float* __restrict__ dis, const float* __restrict__ xw,
                               float* __restrict__ out) {
    long long idx = (long long)blockIdx.x * blockDim.x + threadIdx.x;
    if (idx >= (long long)NE * DOUT) return;
    int e = (int)(idx >> 5);
    int d = (int)(idx & (DOUT - 1));
    int r = row[e];
    int c = col[e];
    atomicAdd(&out[c * DOUT + d], dis[r] * dis[c] * xw[r * DOUT + d]);
}

// ===========================================================================
extern "C" void kernel_launch(void* const* d_in, const int* in_sizes, int n_in,
                              void* d_out, int out_size, void* d_ws, size_t ws_size,
                              hipStream_t stream) {
    const float* x  = (const float*)d_in[0];
    const int*   ei = (const int*)d_in[1];
    const float* W  = (const float*)d_in[2];
    const float* b  = (const float*)d_in[3];
    float* out = (float*)d_out;

    const int* row = ei;       // edge_index[0] = source
    const int* col = ei + NE;  // edge_index[1] = target

    char* ws = (char*)d_ws;
    int*          histmat = (int*)(ws + 0);          //   306,544 B
    int*          bsum    = (int*)(ws + 306560);     //     1,564 B
    int*          base    = (int*)(ws + 308224);     //     1,568 B (NBUK+1)
    int*          offs    = (int*)(ws + 309888);     //   400,004 B (NN+1)
    float*        dis     = (float*)(ws + 710016);   //   400,000 B
    unsigned int* records = (unsigned int*)(ws + 1110144);  // 6,400,000 B
    ushort_t*     xwl     = (ushort_t*)(ws + 7510144);      // 3,200,000 B
    ushort_t*     xwh     = (ushort_t*)(ws + 10710272);     // 3,200,000 B
    ushort_t*     Wht     = (ushort_t*)(ws + 13910272);     //     8,192 B
    const size_t WS_NEEDED = 13918464ull;

    if (ws_size >= WS_NEEDED) {
        hist_kernel<<<FILLB, 256, 0, stream>>>(col, histmat);
        colscan_kernel<<<NBUK, 256, 0, stream>>>(histmat, bsum);
        bscan_wb_kernel<<<9, 512, 0, stream>>>(bsum, base, W, Wht);
        fill_kernel<<<FILLB, 256, 0, stream>>>(row, col, base, histmat, records);
        sort_kernel<<<NBUK, 256, 0, stream>>>(base, records, dis, offs);
        {
            int bl = (NN / 16 + 3) / 4;    // 6250 waves, 4 per block
            xw_kernel<<<bl, 256, 0, stream>>>(x, Wht, dis, xwl, xwh);
        }
        {
            long long threads = (long long)NN * 64;
            int bl = (int)((threads + 255) / 256);
            aggregate_half_kernel<<<bl, 256, 0, stream>>>(offs, (const int*)records, dis, xwl, b, out, 0);
            aggregate_half_kernel<<<bl, 256, 0, stream>>>(offs, (const int*)records, dis, xwh, b, out, 1);
        }
    } else {
        // fallback: atomic scatter path
        int* deg = (int*)(ws + 0);
        float* dis2 = (float*)(ws + 400128);
        float* xw = (float*)(ws + 800256);
        hipMemsetAsync(deg, 0, NN * sizeof(int), stream);
        {
            int th = 256, bl = (NE + th - 1) / th;
            deg_count_kernel<<<bl, th, 0, stream>>>(col, deg);
        }
        {
            int th = 256, bl = (NN + th - 1) / th;
            dis_kernel<<<bl, th, 0, stream>>>(deg, dis2);
        }
        {
            long long total = (long long)NN * DOUT;
            int bl = (int)((total + 255) / 256);
            xw_init_kernel<<<bl, 256, 0, stream>>>(x, W, b, dis2, xw, out);
        }
        {
            long long total = (long long)NE * DOUT;
            int bl = (int)((total + 255) / 256);
            scatter_kernel<<<bl, 256, 0, stream>>>(row, col, dis2, xw, out);
        }
    }
}

// Round 10
// 104.463 us; speedup vs baseline: 1.5135x; 1.5135x over previous
//
#include <hip/hip_runtime.h>

#define NN 100000
#define NE 1600000
#define DIN 128
#define DOUT 32
#define NBUK 391     // ceil(NN/256) buckets of 256 nodes
#define FILLB 196    // edge chunks
#define CHUNK 8192   // edges per chunk (196*8192 >= NE)
#define CAP 8192     // max records per bucket staged in LDS (mean 4092, sd ~64)

typedef unsigned short ushort_t;
typedef unsigned int uint_t;
typedef _Float16 f16x8 __attribute__((ext_vector_type(8)));
typedef float f32x4 __attribute__((ext_vector_type(4)));

static __device__ __forceinline__ ushort_t f2h_u(float f) {
    _Float16 h = (_Float16)f;
    ushort_t u;
    __builtin_memcpy(&u, &h, 2);
    return u;
}
static __device__ __forceinline__ float h2f(ushort_t us) {
    _Float16 h;
    __builtin_memcpy(&h, &us, 2);
    return (float)h;
}

// ===========================================================================
// k1: per-(chunk,bucket) histogram -> histmat[FILLB][NBUK]. LDS atomics only.
// ===========================================================================
__global__ __launch_bounds__(256)
void hist_kernel(const int* __restrict__ col, int* __restrict__ histmat) {
    __shared__ int h[NBUK];
    int t = threadIdx.x, blk = blockIdx.x;
    for (int b = t; b < NBUK; b += 256) h[b] = 0;
    __syncthreads();
    int e0 = blk * CHUNK, emax = min(e0 + CHUNK, NE);
    for (int e = e0 + t; e < emax; e += 256) atomicAdd(&h[col[e] >> 8], 1);
    __syncthreads();
    for (int b = t; b < NBUK; b += 256) histmat[(size_t)blk * NBUK + b] = h[b];
}

// ===========================================================================
// k2a: per-bucket exclusive scan over the 196 chunks (in place) + bucket totals
// ===========================================================================
__global__ __launch_bounds__(256)
void colscan_kernel(int* __restrict__ histmat, int* __restrict__ bsum) {
    __shared__ int s[256];
    int b = blockIdx.x, t = threadIdx.x;
    int v = (t < FILLB) ? histmat[(size_t)t * NBUK + b] : 0;
    s[t] = v;
    __syncthreads();
    for (int off = 1; off < 256; off <<= 1) {
        int u = (t >= off) ? s[t - off] : 0;
        __syncthreads();
        s[t] += u;
        __syncthreads();
    }
    if (t < FILLB) histmat[(size_t)t * NBUK + b] = s[t] - v;  // exclusive
    if (t == FILLB - 1) bsum[b] = s[t];
}

// ===========================================================================
// k2b: block 0: exclusive scan of bucket totals -> base[NBUK+1]
//      blocks 1..8: Wht[c][k] = f16(W[k][c])  (transposed fp16 weights, 8 KB)
// ===========================================================================
__global__ __launch_bounds__(512)
void bscan_wb_kernel(const int* __restrict__ bsum, int* __restrict__ base,
                     const float* __restrict__ W, ushort_t* __restrict__ Wht) {
    if (blockIdx.x == 0) {
        __shared__ int s[512];
        int t = threadIdx.x;
        int own = (t < NBUK) ? bsum[t] : 0;
        s[t] = own;
        __syncthreads();
        for (int off = 1; off < 512; off <<= 1) {
            int v = (t >= off) ? s[t - off] : 0;
            __syncthreads();
            s[t] += v;
            __syncthreads();
        }
        if (t < NBUK) {
            base[t] = s[t] - own;
            if (t == NBUK - 1) base[NBUK] = s[t];
        }
    } else {
        int i = (blockIdx.x - 1) * 512 + threadIdx.x;
        if (i < DIN * DOUT) {
            int c = i >> 7;       // 0..31
            int k = i & 127;      // 0..127
            Wht[(size_t)c * DIN + k] = f2h_u(W[(size_t)k * DOUT + c]);
        }
    }
}

// ===========================================================================
// k3: fill records at deterministic positions (LDS cursors, no global atomics)
// record = (row << 8) | (col & 255)
// ===========================================================================
__global__ __launch_bounds__(256)
void fill_kernel(const int* __restrict__ row, const int* __restrict__ col,
                 const int* __restrict__ base, const int* __restrict__ histmat,
                 unsigned int* __restrict__ records) {
    __shared__ int lcur[NBUK];
    int t = threadIdx.x, blk = blockIdx.x;
    for (int b = t; b < NBUK; b += 256)
        lcur[b] = base[b] + histmat[(size_t)blk * NBUK + b];
    __syncthreads();
    int e0 = blk * CHUNK, emax = min(e0 + CHUNK, NE);
    for (int e = e0 + t; e < emax; e += 256) {
        int c = col[e];
        int slot = atomicAdd(&lcur[c >> 8], 1);
        records[slot] = ((unsigned int)row[e] << 8) | (unsigned int)(c & 255);
    }
}

// ===========================================================================
// k4: per-bucket sort (records -> grouped by node, in place), + deg -> dis,
// + per-node CSR offsets. All writes block-local / coalesced.
// ===========================================================================
__global__ __launch_bounds__(256)
void sort_kernel(const int* __restrict__ base, unsigned int* __restrict__ records,
                 float* __restrict__ dis, int* __restrict__ offs) {
    __shared__ unsigned int stage[CAP];  // 32 KB
    __shared__ int hist[256];
    __shared__ int sc[256];
    __shared__ int lcur[256];
    int b = blockIdx.x, t = threadIdx.x;
    int s = base[b], e = base[b + 1];
    int cnt = e - s;
    hist[t] = 0;
    for (int j = t; j < cnt; j += 256) stage[j] = records[s + j];
    __syncthreads();
    for (int j = t; j < cnt; j += 256) atomicAdd(&hist[stage[j] & 255u], 1);
    __syncthreads();
    int d = hist[t];
    sc[t] = d;
    __syncthreads();
    for (int off = 1; off < 256; off <<= 1) {
        int u = (t >= off) ? sc[t - off] : 0;
        __syncthreads();
        sc[t] += u;
        __syncthreads();
    }
    int excl = sc[t] - d;
    int n = (b << 8) + t;
    if (n < NN) {
        dis[n] = rsqrtf((float)(d + 1));
        offs[n] = s + excl;
        if (n == NN - 1) offs[NN] = e;
    }
    lcur[t] = excl;
    __syncthreads();
    for (int j = t; j < cnt; j += 256) {
        unsigned int rec = stage[j];
        int slot = atomicAdd(&lcur[rec & 255u], 1);
        records[s + slot] = rec >> 8;  // now plain src row id
    }
}

// ===========================================================================
// k5: xwsh[r] = f16( (x[r] @ W) * dis[r] )  via MFMA 16x16x32_f16.
// One wave = 16 rows; 4 waves/block; 6250 waves.
// ===========================================================================
__global__ __launch_bounds__(256)
void xw_kernel(const float* __restrict__ x, const ushort_t* __restrict__ Wht,
               const float* __restrict__ dis, ushort_t* __restrict__ xwsh) {
    int t = threadIdx.x;
    int wv = t >> 6, lane = t & 63;
    int wtile = blockIdx.x * 4 + wv;
    if (wtile >= NN / 16) return;          // uniform per wave
    int r0 = wtile * 16;
    int rowi = lane & 15;                  // A-row / B-col / D-col
    int kg = lane >> 4;                    // k-group (0..3)

    // B fragments: 2 N-tiles x 4 K-steps, 16B each from Wht
    f16x8 bfrag[2][4];
#pragma unroll
    for (int t2 = 0; t2 < 2; ++t2)
#pragma unroll
        for (int s = 0; s < 4; ++s)
            bfrag[t2][s] = *(const f16x8*)(Wht + (size_t)(t2 * 16 + rowi) * DIN + s * 32 + kg * 8);

    // A: row r0+rowi, 8 fp32 per K-step at k = s*32 + kg*8
    const float* __restrict__ xr = x + (size_t)(r0 + rowi) * DIN;
    float4 xa[8];
#pragma unroll
    for (int s = 0; s < 4; ++s) {
        xa[2 * s]     = *(const float4*)(xr + s * 32 + kg * 8);
        xa[2 * s + 1] = *(const float4*)(xr + s * 32 + kg * 8 + 4);
    }
    f16x8 afrag[4];
#pragma unroll
    for (int s = 0; s < 4; ++s) {
        f16x8 a;
        a[0] = (_Float16)xa[2 * s].x;     a[1] = (_Float16)xa[2 * s].y;
        a[2] = (_Float16)xa[2 * s].z;     a[3] = (_Float16)xa[2 * s].w;
        a[4] = (_Float16)xa[2 * s + 1].x; a[5] = (_Float16)xa[2 * s + 1].y;
        a[6] = (_Float16)xa[2 * s + 1].z; a[7] = (_Float16)xa[2 * s + 1].w;
        afrag[s] = a;
    }

    f32x4 acc0 = {0.f, 0.f, 0.f, 0.f};
    f32x4 acc1 = {0.f, 0.f, 0.f, 0.f};
#pragma unroll
    for (int s = 0; s < 4; ++s) {
        acc0 = __builtin_amdgcn_mfma_f32_16x16x32_f16(afrag[s], bfrag[0][s], acc0, 0, 0, 0);
        acc1 = __builtin_amdgcn_mfma_f32_16x16x32_f16(afrag[s], bfrag[1][s], acc1, 0, 0, 0);
    }

    // D[row = kg*4+j][col = rowi]; scale by dis[row], store f16
#pragma unroll
    for (int j = 0; j < 4; ++j) {
        int orow = r0 + kg * 4 + j;
        float dv = dis[orow];
        xwsh[(size_t)orow * DOUT + rowi]      = f2h_u(acc0[j] * dv);
        xwsh[(size_t)orow * DOUT + 16 + rowi] = f2h_u(acc1[j] * dv);
    }
}

// ===========================================================================
// k6: aggregate, zero-reduce layout. Half-wave (32 lanes) = one node; lane
// owns one output dim and serially walks the node's edge list. Per edge the
// 32 lanes read one coalesced 64B row (u16/lane); f32 accumulate; unroll 8
// keeps 8 gathers in flight. No cross-lane reduction at all.
// ===========================================================================
__global__ __launch_bounds__(256)
void aggregate_kernel(const int* __restrict__ offs, const int* __restrict__ srcs,
                      const float* __restrict__ dis, const ushort_t* __restrict__ xwsh,
                      const float* __restrict__ bias, float* __restrict__ out) {
    int gw = (int)((blockIdx.x * (long long)blockDim.x + threadIdx.x) >> 6);
    int half = (threadIdx.x >> 5) & 1;
    int wid = gw * 2 + half;
    if (wid >= NN) return;
    int d = threadIdx.x & 31;

    int s = offs[wid], e = offs[wid + 1];
    float acc = h2f(xwsh[((size_t)wid << 5) + d]);   // self-loop
    int i = s;
    for (; i + 8 <= e; i += 8) {
        int r0 = srcs[i + 0], r1 = srcs[i + 1], r2 = srcs[i + 2], r3 = srcs[i + 3];
        int r4 = srcs[i + 4], r5 = srcs[i + 5], r6 = srcs[i + 6], r7 = srcs[i + 7];
        ushort_t u0 = xwsh[((size_t)r0 << 5) + d];
        ushort_t u1 = xwsh[((size_t)r1 << 5) + d];
        ushort_t u2 = xwsh[((size_t)r2 << 5) + d];
        ushort_t u3 = xwsh[((size_t)r3 << 5) + d];
        ushort_t u4 = xwsh[((size_t)r4 << 5) + d];
        ushort_t u5 = xwsh[((size_t)r5 << 5) + d];
        ushort_t u6 = xwsh[((size_t)r6 << 5) + d];
        ushort_t u7 = xwsh[((size_t)r7 << 5) + d];
        acc += h2f(u0); acc += h2f(u1); acc += h2f(u2); acc += h2f(u3);
        acc += h2f(u4); acc += h2f(u5); acc += h2f(u6); acc += h2f(u7);
    }
    if (i + 4 <= e) {
        int r0 = srcs[i + 0], r1 = srcs[i + 1], r2 = srcs[i + 2], r3 = srcs[i + 3];
        ushort_t u0 = xwsh[((size_t)r0 << 5) + d];
        ushort_t u1 = xwsh[((size_t)r1 << 5) + d];
        ushort_t u2 = xwsh[((size_t)r2 << 5) + d];
        ushort_t u3 = xwsh[((size_t)r3 << 5) + d];
        acc += h2f(u0); acc += h2f(u1); acc += h2f(u2); acc += h2f(u3);
        i += 4;
    }
    for (; i < e; ++i) acc += h2f(xwsh[((size_t)srcs[i] << 5) + d]);

    out[((size_t)wid << 5) + d] = dis[wid] * acc + bias[d];
}

// ===========================================================================
// Fallback path (R1) if workspace is too small
// ===========================================================================
__global__ void deg_count_kernel(const int* __restrict__ col, int* __restrict__ deg) {
    int e = blockIdx.x * blockDim.x + threadIdx.x;
    if (e < NE) atomicAdd(&deg[col[e]], 1);
}
__global__ void dis_kernel(const int* __restrict__ deg, float* __restrict__ dis) {
    int i = blockIdx.x * blockDim.x + threadIdx.x;
    if (i < NN) dis[i] = rsqrtf((float)(deg[i] + 1));
}
__global__ void xw_init_kernel(const float* __restrict__ x, const float* __restrict__ W,
                               const float* __restrict__ b, const float* __restrict__ dis,
                               float* __restrict__ xw, float* __restrict__ out) {
    __shared__ float Ws[DIN * DOUT];
    for (int i = threadIdx.x; i < DIN * DOUT; i += blockDim.x) Ws[i] = W[i];
    __syncthreads();
    int idx = blockIdx.x * blockDim.x + threadIdx.x;
    if (idx >= NN * DOUT) return;
    int n = idx >> 5;
    int d = idx & (DOUT - 1);
    const float* xr = x + (long long)n * DIN;
    float acc = 0.f;
#pragma unroll
    for (int k = 0; k < DIN; ++k) acc += xr[k] * Ws[k * DOUT + d];
    xw[idx] = acc;
    float di = dis[n];
    out[idx] = di * di * acc + b[d];
}
__global__ void scatter_kernel(const int* __restrict__ row, const int* __restrict__ col,
                               const float* __restrict__ dis, const float* __restrict__ xw,
                               float* __restrict__ out) {
    long long idx = (long long)blockIdx.x * blockDim.x + threadIdx.x;
    if (idx >= (long long)NE * DOUT) return;
    int e = (int)(idx >> 5);
    int d = (int)(idx & (DOUT - 1));
    int r = row[e];
    int c = col[e];
    atomicAdd(&out[c * DOUT + d], dis[r] * dis[c] * xw[r * DOUT + d]);
}

// ===========================================================================
extern "C" void kernel_launch(void* const* d_in, const int* in_sizes, int n_in,
                              void* d_out, int out_size, void* d_ws, size_t ws_size,
                              hipStream_t stream) {
    const float* x  = (const float*)d_in[0];
    const int*   ei = (const int*)d_in[1];
    const float* W  = (const float*)d_in[2];
    const float* b  = (const float*)d_in[3];
    float* out = (float*)d_out;

    const int* row = ei;       // edge_index[0] = source
    const int* col = ei + NE;  // edge_index[1] = target

    char* ws = (char*)d_ws;
    int*          histmat = (int*)(ws + 0);          //   306,544 B
    int*          bsum    = (int*)(ws + 306560);     //     1,564 B
    int*          base    = (int*)(ws + 308224);     //     1,568 B (NBUK+1)
    int*          offs    = (int*)(ws + 309888);     //   400,004 B (NN+1)
    float*        dis     = (float*)(ws + 710016);   //   400,000 B
    unsigned int* records = (unsigned int*)(ws + 1110144);  // 6,400,000 B
    ushort_t*     xwsh    = (ushort_t*)(ws + 7510144);      // 6,400,000 B
    ushort_t*     Wht     = (ushort_t*)(ws + 13910144);     //     8,192 B
    const size_t WS_NEEDED = 13918336ull;

    if (ws_size >= WS_NEEDED) {
        hist_kernel<<<FILLB, 256, 0, stream>>>(col, histmat);
        colscan_kernel<<<NBUK, 256, 0, stream>>>(histmat, bsum);
        bscan_wb_kernel<<<9, 512, 0, stream>>>(bsum, base, W, Wht);
        fill_kernel<<<FILLB, 256, 0, stream>>>(row, col, base, histmat, records);
        sort_kernel<<<NBUK, 256, 0, stream>>>(base, records, dis, offs);
        {
            int bl = (NN / 16 + 3) / 4;    // 6250 waves, 4 per block
            xw_kernel<<<bl, 256, 0, stream>>>(x, Wht, dis, xwsh);
        }
        {
            long long waves = (NN + 1) / 2;             // 2 nodes per wave
            int bl = (int)((waves + 3) / 4);            // 4 waves per block
            aggregate_kernel<<<bl, 256, 0, stream>>>(offs, (const int*)records, dis, xwsh, b, out);
        }
    } else {
        // fallback: atomic scatter path
        int* deg = (int*)(ws + 0);
        float* dis2 = (float*)(ws + 400128);
        float* xw = (float*)(ws + 800256);
        hipMemsetAsync(deg, 0, NN * sizeof(int), stream);
        {
            int th = 256, bl = (NE + th - 1) / th;
            deg_count_kernel<<<bl, th, 0, stream>>>(col, deg);
        }
        {
            int th = 256, bl = (NN + th - 1) / th;
            dis_kernel<<<bl, th, 0, stream>>>(deg, dis2);
        }
        {
            long long total = (long long)NN * DOUT;
            int bl = (int)((total + 255) / 256);
            xw_init_kernel<<<bl, 256, 0, stream>>>(x, W, b, dis2, xw, out);
        }
        {
            long long total = (long long)NE * DOUT;
            int bl = (int)((total + 255) / 256);
            scatter_kernel<<<bl, 256, 0, stream>>>(row, col, dis2, xw, out);
        }
    }
}

// Round 11
// 96.227 us; speedup vs baseline: 1.6430x; 1.0856x over previous
//
#include <hip/hip_runtime.h>

#define NN 100000
#define NE 1600000
#define DIN 128
#define DOUT 32
#define NBUK 391     // ceil(NN/256) buckets of 256 nodes
#define FILLB 512    // edge chunks (512*3125 = NE exactly)
#define CHUNK 3125   // edges per chunk
#define CAP 8192     // max records per bucket staged in LDS (mean 4092, sd ~64)

typedef unsigned short ushort_t;
typedef unsigned int uint_t;
typedef _Float16 f16x8 __attribute__((ext_vector_type(8)));
typedef float f32x4 __attribute__((ext_vector_type(4)));

static __device__ __forceinline__ ushort_t f2h_u(float f) {
    _Float16 h = (_Float16)f;
    ushort_t u;
    __builtin_memcpy(&u, &h, 2);
    return u;
}
static __device__ __forceinline__ float h2f(ushort_t us) {
    _Float16 h;
    __builtin_memcpy(&h, &us, 2);
    return (float)h;
}

// ===========================================================================
// k1: per-(chunk,bucket) histogram -> histmat[FILLB][NBUK]. LDS atomics only.
// 512 blocks (2/CU) for latency hiding.
// ===========================================================================
__global__ __launch_bounds__(256)
void hist_kernel(const int* __restrict__ col, int* __restrict__ histmat) {
    __shared__ int h[NBUK];
    int t = threadIdx.x, blk = blockIdx.x;
    for (int b = t; b < NBUK; b += 256) h[b] = 0;
    __syncthreads();
    int e0 = blk * CHUNK, emax = min(e0 + CHUNK, NE);
    for (int e = e0 + t; e < emax; e += 256) atomicAdd(&h[col[e] >> 8], 1);
    __syncthreads();
    for (int b = t; b < NBUK; b += 256) histmat[(size_t)blk * NBUK + b] = h[b];
}

// ===========================================================================
// k2a: per-bucket exclusive scan over the 512 chunks (in place) + bucket totals
// 512 threads scan the 512 chunk-entries directly.
// ===========================================================================
__global__ __launch_bounds__(512)
void colscan_kernel(int* __restrict__ histmat, int* __restrict__ bsum) {
    __shared__ int s[512];
    int b = blockIdx.x, t = threadIdx.x;
    int v = histmat[(size_t)t * NBUK + b];   // FILLB == 512 == blockDim
    s[t] = v;
    __syncthreads();
    for (int off = 1; off < 512; off <<= 1) {
        int u = (t >= off) ? s[t - off] : 0;
        __syncthreads();
        s[t] += u;
        __syncthreads();
    }
    histmat[(size_t)t * NBUK + b] = s[t] - v;  // exclusive
    if (t == FILLB - 1) bsum[b] = s[t];
}

// ===========================================================================
// k2b: block 0: exclusive scan of bucket totals -> base[NBUK+1]
//      blocks 1..8: Wht[c][k] = f16(W[k][c])  (transposed fp16 weights, 8 KB)
// ===========================================================================
__global__ __launch_bounds__(512)
void bscan_wb_kernel(const int* __restrict__ bsum, int* __restrict__ base,
                     const float* __restrict__ W, ushort_t* __restrict__ Wht) {
    if (blockIdx.x == 0) {
        __shared__ int s[512];
        int t = threadIdx.x;
        int own = (t < NBUK) ? bsum[t] : 0;
        s[t] = own;
        __syncthreads();
        for (int off = 1; off < 512; off <<= 1) {
            int v = (t >= off) ? s[t - off] : 0;
            __syncthreads();
            s[t] += v;
            __syncthreads();
        }
        if (t < NBUK) {
            base[t] = s[t] - own;
            if (t == NBUK - 1) base[NBUK] = s[t];
        }
    } else {
        int i = (blockIdx.x - 1) * 512 + threadIdx.x;
        if (i < DIN * DOUT) {
            int c = i >> 7;       // 0..31
            int k = i & 127;      // 0..127
            Wht[(size_t)c * DIN + k] = f2h_u(W[(size_t)k * DOUT + c]);
        }
    }
}

// ===========================================================================
// k3: fill records at deterministic positions (LDS cursors, no global atomics)
// record = (row << 8) | (col & 255).  512 blocks.
// ===========================================================================
__global__ __launch_bounds__(256)
void fill_kernel(const int* __restrict__ row, const int* __restrict__ col,
                 const int* __restrict__ base, const int* __restrict__ histmat,
                 unsigned int* __restrict__ records) {
    __shared__ int lcur[NBUK];
    int t = threadIdx.x, blk = blockIdx.x;
    for (int b = t; b < NBUK; b += 256)
        lcur[b] = base[b] + histmat[(size_t)blk * NBUK + b];
    __syncthreads();
    int e0 = blk * CHUNK, emax = min(e0 + CHUNK, NE);
    for (int e = e0 + t; e < emax; e += 256) {
        int c = col[e];
        int slot = atomicAdd(&lcur[c >> 8], 1);
        records[slot] = ((unsigned int)row[e] << 8) | (unsigned int)(c & 255);
    }
}

// ===========================================================================
// k4: per-bucket sort (records -> grouped by node, in place), + deg -> dis,
// + per-node CSR offsets. 512 threads/block (3 waves/SIMD grid occupancy).
// ===========================================================================
__global__ __launch_bounds__(512)
void sort_kernel(const int* __restrict__ base, unsigned int* __restrict__ records,
                 float* __restrict__ dis, int* __restrict__ offs) {
    __shared__ unsigned int stage[CAP];  // 32 KB
    __shared__ int hist[256];
    __shared__ int sc[256];
    __shared__ int lcur[256];
    int b = blockIdx.x, t = threadIdx.x;
    int s = base[b], e = base[b + 1];
    int cnt = e - s;
    if (t < 256) hist[t] = 0;
    for (int j = t; j < cnt; j += 512) stage[j] = records[s + j];
    __syncthreads();
    for (int j = t; j < cnt; j += 512) atomicAdd(&hist[stage[j] & 255u], 1);
    __syncthreads();
    int d = (t < 256) ? hist[t] : 0;
    if (t < 256) sc[t] = d;
    __syncthreads();
    for (int off = 1; off < 256; off <<= 1) {
        int u = (t < 256 && t >= off) ? sc[t - off] : 0;
        __syncthreads();
        if (t < 256) sc[t] += u;
        __syncthreads();
    }
    if (t < 256) {
        int excl = sc[t] - d;
        int n = (b << 8) + t;
        if (n < NN) {
            dis[n] = rsqrtf((float)(d + 1));
            offs[n] = s + excl;
            if (n == NN - 1) offs[NN] = e;
        }
        lcur[t] = excl;
    }
    __syncthreads();
    for (int j = t; j < cnt; j += 512) {
        unsigned int rec = stage[j];
        int slot = atomicAdd(&lcur[rec & 255u], 1);
        records[s + slot] = rec >> 8;  // now plain src row id
    }
}

// ===========================================================================
// k5: xwsh[r] = f16( (x[r] @ W) * dis[r] )  via MFMA 16x16x32_f16.
// One wave = 16 rows; 4 waves/block; 6250 waves.
// ===========================================================================
__global__ __launch_bounds__(256)
void xw_kernel(const float* __restrict__ x, const ushort_t* __restrict__ Wht,
               const float* __restrict__ dis, ushort_t* __restrict__ xwsh) {
    int t = threadIdx.x;
    int wv = t >> 6, lane = t & 63;
    int wtile = blockIdx.x * 4 + wv;
    if (wtile >= NN / 16) return;          // uniform per wave
    int r0 = wtile * 16;
    int rowi = lane & 15;                  // A-row / B-col / D-col
    int kg = lane >> 4;                    // k-group (0..3)

    // B fragments: 2 N-tiles x 4 K-steps, 16B each from Wht
    f16x8 bfrag[2][4];
#pragma unroll
    for (int t2 = 0; t2 < 2; ++t2)
#pragma unroll
        for (int s = 0; s < 4; ++s)
            bfrag[t2][s] = *(const f16x8*)(Wht + (size_t)(t2 * 16 + rowi) * DIN + s * 32 + kg * 8);

    // A: row r0+rowi, 8 fp32 per K-step at k = s*32 + kg*8
    const float* __restrict__ xr = x + (size_t)(r0 + rowi) * DIN;
    float4 xa[8];
#pragma unroll
    for (int s = 0; s < 4; ++s) {
        xa[2 * s]     = *(const float4*)(xr + s * 32 + kg * 8);
        xa[2 * s + 1] = *(const float4*)(xr + s * 32 + kg * 8 + 4);
    }
    f16x8 afrag[4];
#pragma unroll
    for (int s = 0; s < 4; ++s) {
        f16x8 a;
        a[0] = (_Float16)xa[2 * s].x;     a[1] = (_Float16)xa[2 * s].y;
        a[2] = (_Float16)xa[2 * s].z;     a[3] = (_Float16)xa[2 * s].w;
        a[4] = (_Float16)xa[2 * s + 1].x; a[5] = (_Float16)xa[2 * s + 1].y;
        a[6] = (_Float16)xa[2 * s + 1].z; a[7] = (_Float16)xa[2 * s + 1].w;
        afrag[s] = a;
    }

    f32x4 acc0 = {0.f, 0.f, 0.f, 0.f};
    f32x4 acc1 = {0.f, 0.f, 0.f, 0.f};
#pragma unroll
    for (int s = 0; s < 4; ++s) {
        acc0 = __builtin_amdgcn_mfma_f32_16x16x32_f16(afrag[s], bfrag[0][s], acc0, 0, 0, 0);
        acc1 = __builtin_amdgcn_mfma_f32_16x16x32_f16(afrag[s], bfrag[1][s], acc1, 0, 0, 0);
    }

    // D[row = kg*4+j][col = rowi]; scale by dis[row], store f16
#pragma unroll
    for (int j = 0; j < 4; ++j) {
        int orow = r0 + kg * 4 + j;
        float dv = dis[orow];
        xwsh[(size_t)orow * DOUT + rowi]      = f2h_u(acc0[j] * dv);
        xwsh[(size_t)orow * DOUT + 16 + rowi] = f2h_u(acc1[j] * dv);
    }
}

// ===========================================================================
// k6: aggregate, zero-reduce layout. Half-wave (32 lanes) = one node; lane
// owns one output dim and serially walks the node's edge list. Per edge the
// 32 lanes read one coalesced 64B row (u16/lane); f32 accumulate; unroll 8
// keeps 8 gathers in flight. No cross-lane reduction at all.
// ===========================================================================
__global__ __launch_bounds__(256)
void aggregate_kernel(const int* __restrict__ offs, const int* __restrict__ srcs,
                      const float* __restrict__ dis, const ushort_t* __restrict__ xwsh,
                      const float* __restrict__ bias, float* __restrict__ out) {
    int gw = (int)((blockIdx.x * (long long)blockDim.x + threadIdx.x) >> 6);
    int half = (threadIdx.x >> 5) & 1;
    int wid = gw * 2 + half;
    if (wid >= NN) return;
    int d = threadIdx.x & 31;

    int s = offs[wid], e = offs[wid + 1];
    float acc = h2f(xwsh[((size_t)wid << 5) + d]);   // self-loop
    int i = s;
    for (; i + 8 <= e; i += 8) {
        int r0 = srcs[i + 0], r1 = srcs[i + 1], r2 = srcs[i + 2], r3 = srcs[i + 3];
        int r4 = srcs[i + 4], r5 = srcs[i + 5], r6 = srcs[i + 6], r7 = srcs[i + 7];
        ushort_t u0 = xwsh[((size_t)r0 << 5) + d];
        ushort_t u1 = xwsh[((size_t)r1 << 5) + d];
        ushort_t u2 = xwsh[((size_t)r2 << 5) + d];
        ushort_t u3 = xwsh[((size_t)r3 << 5) + d];
        ushort_t u4 = xwsh[((size_t)r4 << 5) + d];
        ushort_t u5 = xwsh[((size_t)r5 << 5) + d];
        ushort_t u6 = xwsh[((size_t)r6 << 5) + d];
        ushort_t u7 = xwsh[((size_t)r7 << 5) + d];
        acc += h2f(u0); acc += h2f(u1); acc += h2f(u2); acc += h2f(u3);
        acc += h2f(u4); acc += h2f(u5); acc += h2f(u6); acc += h2f(u7);
    }
    if (i + 4 <= e) {
        int r0 = srcs[i + 0], r1 = srcs[i + 1], r2 = srcs[i + 2], r3 = srcs[i + 3];
        ushort_t u0 = xwsh[((size_t)r0 << 5) + d];
        ushort_t u1 = xwsh[((size_t)r1 << 5) + d];
        ushort_t u2 = xwsh[((size_t)r2 << 5) + d];
        ushort_t u3 = xwsh[((size_t)r3 << 5) + d];
        acc += h2f(u0); acc += h2f(u1); acc += h2f(u2); acc += h2f(u3);
        i += 4;
    }
    for (; i < e; ++i) acc += h2f(xwsh[((size_t)srcs[i] << 5) + d]);

    out[((size_t)wid << 5) + d] = dis[wid] * acc + bias[d];
}

// ===========================================================================
// Fallback path (R1) if workspace is too small
// ===========================================================================
__global__ void deg_count_kernel(const int* __restrict__ col, int* __restrict__ deg) {
    int e = blockIdx.x * blockDim.x + threadIdx.x;
    if (e < NE) atomicAdd(&deg[col[e]], 1);
}
__global__ void dis_kernel(const int* __restrict__ deg, float* __restrict__ dis) {
    int i = blockIdx.x * blockDim.x + threadIdx.x;
    if (i < NN) dis[i] = rsqrtf((float)(deg[i] + 1));
}
__global__ void xw_init_kernel(const float* __restrict__ x, const float* __restrict__ W,
                               const float* __restrict__ b, const float* __restrict__ dis,
                               float* __restrict__ xw, float* __restrict__ out) {
    __shared__ float Ws[DIN * DOUT];
    for (int i = threadIdx.x; i < DIN * DOUT; i += blockDim.x) Ws[i] = W[i];
    __syncthreads();
    int idx = blockIdx.x * blockDim.x + threadIdx.x;
    if (idx >= NN * DOUT) return;
    int n = idx >> 5;
    int d = idx & (DOUT - 1);
    const float* xr = x + (long long)n * DIN;
    float acc = 0.f;
#pragma unroll
    for (int k = 0; k < DIN; ++k) acc += xr[k] * Ws[k * DOUT + d];
    xw[idx] = acc;
    float di = dis[n];
    out[idx] = di * di * acc + b[d];
}
__global__ void scatter_kernel(const int* __restrict__ row, const int* __restrict__ col,
                               const float* __restrict__ dis, const float* __restrict__ xw,
                               float* __restrict__ out) {
    long long idx = (long long)blockIdx.x * blockDim.x + threadIdx.x;
    if (idx >= (long long)NE * DOUT) return;
    int e = (int)(idx >> 5);
    int d = (int)(idx & (DOUT - 1));
    int r = row[e];
    int c = col[e];
    atomicAdd(&out[c * DOUT + d], dis[r] * dis[c] * xw[r * DOUT + d]);
}

// ===========================================================================
extern "C" void kernel_launch(void* const* d_in, const int* in_sizes, int n_in,
                              void* d_out, int out_size, void* d_ws, size_t ws_size,
                              hipStream_t stream) {
    const float* x  = (const float*)d_in[0];
    const int*   ei = (const int*)d_in[1];
    const float* W  = (const float*)d_in[2];
    const float* b  = (const float*)d_in[3];
    float* out = (float*)d_out;

    const int* row = ei;       // edge_index[0] = source
    const int* col = ei + NE;  // edge_index[1] = target

    char* ws = (char*)d_ws;
    int*          histmat = (int*)(ws + 0);          //   800,768 B (512*391*4)
    int*          bsum    = (int*)(ws + 800768);     //     1,564 B
    int*          base    = (int*)(ws + 802432);     //     1,568 B (NBUK+1)
    int*          offs    = (int*)(ws + 804096);     //   400,004 B (NN+1)
    float*        dis     = (float*)(ws + 1204224);  //   400,000 B
    unsigned int* records = (unsigned int*)(ws + 1604352);  // 6,400,000 B
    ushort_t*     xwsh    = (ushort_t*)(ws + 8004352);      // 6,400,000 B
    ushort_t*     Wht     = (ushort_t*)(ws + 14404352);     //     8,192 B
    const size_t WS_NEEDED = 14412544ull;

    if (ws_size >= WS_NEEDED) {
        hist_kernel<<<FILLB, 256, 0, stream>>>(col, histmat);
        colscan_kernel<<<NBUK, 512, 0, stream>>>(histmat, bsum);
        bscan_wb_kernel<<<9, 512, 0, stream>>>(bsum, base, W, Wht);
        fill_kernel<<<FILLB, 256, 0, stream>>>(row, col, base, histmat, records);
        sort_kernel<<<NBUK, 512, 0, stream>>>(base, records, dis, offs);
        {
            int bl = (NN / 16 + 3) / 4;    // 6250 waves, 4 per block
            xw_kernel<<<bl, 256, 0, stream>>>(x, Wht, dis, xwsh);
        }
        {
            long long waves = (NN + 1) / 2;             // 2 nodes per wave
            int bl = (int)((waves + 3) / 4);            // 4 waves per block
            aggregate_kernel<<<bl, 256, 0, stream>>>(offs, (const int*)records, dis, xwsh, b, out);
        }
    } else {
        // fallback: atomic scatter path
        int* deg = (int*)(ws + 0);
        float* dis2 = (float*)(ws + 400128);
        float* xw = (float*)(ws + 800256);
        hipMemsetAsync(deg, 0, NN * sizeof(int), stream);
        {
            int th = 256, bl = (NE + th - 1) / th;
            deg_count_kernel<<<bl, th, 0, stream>>>(col, deg);
        }
        {
            int th = 256, bl = (NN + th - 1) / th;
            dis_kernel<<<bl, th, 0, stream>>>(deg, dis2);
        }
        {
            long long total = (long long)NN * DOUT;
            int bl = (int)((total + 255) / 256);
            xw_init_kernel<<<bl, 256, 0, stream>>>(x, W, b, dis2, xw, out);
        }
        {
            long long total = (long long)NE * DOUT;
            int bl = (int)((total + 255) / 256);
            scatter_kernel<<<bl, 256, 0, stream>>>(row, col, dis2, xw, out);
        }
    }
}

// Round 12
// 95.411 us; speedup vs baseline: 1.6571x; 1.0085x over previous
//
#include <hip/hip_runtime.h>

#define NN 100000
#define NE 1600000
#define DIN 128
#define DOUT 32
#define NBUK 391     // ceil(NN/256) buckets of 256 nodes
#define FILLB 512    // edge chunks (512*3125 = NE exactly)
#define CHUNK 3125   // edges per chunk
#define CAP 8192     // max records per bucket staged in LDS (mean 4092, sd ~64)
#define XWB 1563     // xw blocks (4 waves * 16 rows = 64 rows each)

typedef unsigned short ushort_t;
typedef unsigned int uint_t;
typedef _Float16 f16x8 __attribute__((ext_vector_type(8)));
typedef float f32x4 __attribute__((ext_vector_type(4)));

static __device__ __forceinline__ ushort_t f2h_u(float f) {
    _Float16 h = (_Float16)f;
    ushort_t u;
    __builtin_memcpy(&u, &h, 2);
    return u;
}
static __device__ __forceinline__ float h2f(ushort_t us) {
    _Float16 h;
    __builtin_memcpy(&h, &us, 2);
    return (float)h;
}

// ===========================================================================
// k1: per-(chunk,bucket) histogram -> histmat[FILLB][NBUK]. LDS atomics only.
// ===========================================================================
__global__ __launch_bounds__(256)
void hist_kernel(const int* __restrict__ col, int* __restrict__ histmat) {
    __shared__ int h[NBUK];
    int t = threadIdx.x, blk = blockIdx.x;
    for (int b = t; b < NBUK; b += 256) h[b] = 0;
    __syncthreads();
    int e0 = blk * CHUNK, emax = min(e0 + CHUNK, NE);
    for (int e = e0 + t; e < emax; e += 256) atomicAdd(&h[col[e] >> 8], 1);
    __syncthreads();
    for (int b = t; b < NBUK; b += 256) histmat[(size_t)blk * NBUK + b] = h[b];
}

// ===========================================================================
// k2a: per-bucket exclusive scan over the 512 chunks (in place) + bucket totals
// ===========================================================================
__global__ __launch_bounds__(512)
void colscan_kernel(int* __restrict__ histmat, int* __restrict__ bsum) {
    __shared__ int s[512];
    int b = blockIdx.x, t = threadIdx.x;
    int v = histmat[(size_t)t * NBUK + b];   // FILLB == 512 == blockDim
    s[t] = v;
    __syncthreads();
    for (int off = 1; off < 512; off <<= 1) {
        int u = (t >= off) ? s[t - off] : 0;
        __syncthreads();
        s[t] += u;
        __syncthreads();
    }
    histmat[(size_t)t * NBUK + b] = s[t] - v;  // exclusive
    if (t == FILLB - 1) bsum[b] = s[t];
}

// ===========================================================================
// k2b: block 0: exclusive scan of bucket totals -> base[NBUK+1]
//      blocks 1..8: Wht[c][k] = f16(W[k][c])  (transposed fp16 weights, 8 KB)
// ===========================================================================
__global__ __launch_bounds__(512)
void bscan_wb_kernel(const int* __restrict__ bsum, int* __restrict__ base,
                     const float* __restrict__ W, ushort_t* __restrict__ Wht) {
    if (blockIdx.x == 0) {
        __shared__ int s[512];
        int t = threadIdx.x;
        int own = (t < NBUK) ? bsum[t] : 0;
        s[t] = own;
        __syncthreads();
        for (int off = 1; off < 512; off <<= 1) {
            int v = (t >= off) ? s[t - off] : 0;
            __syncthreads();
            s[t] += v;
            __syncthreads();
        }
        if (t < NBUK) {
            base[t] = s[t] - own;
            if (t == NBUK - 1) base[NBUK] = s[t];
        }
    } else {
        int i = (blockIdx.x - 1) * 512 + threadIdx.x;
        if (i < DIN * DOUT) {
            int c = i >> 7;       // 0..31
            int k = i & 127;      // 0..127
            Wht[(size_t)c * DIN + k] = f2h_u(W[(size_t)k * DOUT + c]);
        }
    }
}

// ===========================================================================
// k3: FUSED fill + xw.
// Blocks [0, FILLB): fill records at deterministic positions (LDS cursors).
// Blocks [FILLB, FILLB+XWB): xwsh[r] = f16(x[r] @ W) via MFMA (UNscaled —
// dis scaling is applied later in sort's epilogue). The two block families
// co-schedule across CUs: fill's scattered-write latency hides under xw's
// MFMA + x-load stream.
// ===========================================================================
__global__ __launch_bounds__(256)
void fill_xw_kernel(const int* __restrict__ row, const int* __restrict__ col,
                    const int* __restrict__ base, const int* __restrict__ histmat,
                    unsigned int* __restrict__ records,
                    const float* __restrict__ x, const ushort_t* __restrict__ Wht,
                    ushort_t* __restrict__ xwsh) {
    __shared__ int lcur[NBUK];
    if (blockIdx.x < FILLB) {
        int t = threadIdx.x, blk = blockIdx.x;
        for (int b = t; b < NBUK; b += 256)
            lcur[b] = base[b] + histmat[(size_t)blk * NBUK + b];
        __syncthreads();
        int e0 = blk * CHUNK, emax = min(e0 + CHUNK, NE);
        for (int e = e0 + t; e < emax; e += 256) {
            int c = col[e];
            int slot = atomicAdd(&lcur[c >> 8], 1);
            records[slot] = ((unsigned int)row[e] << 8) | (unsigned int)(c & 255);
        }
        return;
    }
    // ---- xw part ----
    int t = threadIdx.x;
    int wv = t >> 6, lane = t & 63;
    int wtile = (blockIdx.x - FILLB) * 4 + wv;
    if (wtile >= NN / 16) return;          // uniform per wave
    int r0 = wtile * 16;
    int rowi = lane & 15;                  // A-row / B-col / D-col
    int kg = lane >> 4;                    // k-group (0..3)

    f16x8 bfrag[2][4];
#pragma unroll
    for (int t2 = 0; t2 < 2; ++t2)
#pragma unroll
        for (int s = 0; s < 4; ++s)
            bfrag[t2][s] = *(const f16x8*)(Wht + (size_t)(t2 * 16 + rowi) * DIN + s * 32 + kg * 8);

    const float* __restrict__ xr = x + (size_t)(r0 + rowi) * DIN;
    float4 xa[8];
#pragma unroll
    for (int s = 0; s < 4; ++s) {
        xa[2 * s]     = *(const float4*)(xr + s * 32 + kg * 8);
        xa[2 * s + 1] = *(const float4*)(xr + s * 32 + kg * 8 + 4);
    }
    f16x8 afrag[4];
#pragma unroll
    for (int s = 0; s < 4; ++s) {
        f16x8 a;
        a[0] = (_Float16)xa[2 * s].x;     a[1] = (_Float16)xa[2 * s].y;
        a[2] = (_Float16)xa[2 * s].z;     a[3] = (_Float16)xa[2 * s].w;
        a[4] = (_Float16)xa[2 * s + 1].x; a[5] = (_Float16)xa[2 * s + 1].y;
        a[6] = (_Float16)xa[2 * s + 1].z; a[7] = (_Float16)xa[2 * s + 1].w;
        afrag[s] = a;
    }

    f32x4 acc0 = {0.f, 0.f, 0.f, 0.f};
    f32x4 acc1 = {0.f, 0.f, 0.f, 0.f};
#pragma unroll
    for (int s = 0; s < 4; ++s) {
        acc0 = __builtin_amdgcn_mfma_f32_16x16x32_f16(afrag[s], bfrag[0][s], acc0, 0, 0, 0);
        acc1 = __builtin_amdgcn_mfma_f32_16x16x32_f16(afrag[s], bfrag[1][s], acc1, 0, 0, 0);
    }

    // D[row = kg*4+j][col = rowi]; store UNscaled f16
#pragma unroll
    for (int j = 0; j < 4; ++j) {
        int orow = r0 + kg * 4 + j;
        xwsh[(size_t)orow * DOUT + rowi]      = f2h_u(acc0[j]);
        xwsh[(size_t)orow * DOUT + 16 + rowi] = f2h_u(acc1[j]);
    }
}

// ===========================================================================
// k4: per-bucket sort (records -> grouped by node, in place), + deg -> dis,
// + per-node CSR offsets, + EPILOGUE: scale this bucket's xwsh rows by dis.
// 512 threads/block.
// ===========================================================================
__global__ __launch_bounds__(512)
void sort_kernel(const int* __restrict__ base, unsigned int* __restrict__ records,
                 float* __restrict__ dis, int* __restrict__ offs,
                 ushort_t* __restrict__ xwsh) {
    __shared__ unsigned int stage[CAP];  // 32 KB
    __shared__ int hist[256];
    __shared__ int sc[256];
    __shared__ int lcur[256];
    __shared__ float disL[256];
    int b = blockIdx.x, t = threadIdx.x;
    int s = base[b], e = base[b + 1];
    int cnt = e - s;
    if (t < 256) hist[t] = 0;
    for (int j = t; j < cnt; j += 512) stage[j] = records[s + j];
    __syncthreads();
    for (int j = t; j < cnt; j += 512) atomicAdd(&hist[stage[j] & 255u], 1);
    __syncthreads();
    int d = (t < 256) ? hist[t] : 0;
    if (t < 256) sc[t] = d;
    __syncthreads();
    for (int off = 1; off < 256; off <<= 1) {
        int u = (t < 256 && t >= off) ? sc[t - off] : 0;
        __syncthreads();
        if (t < 256) sc[t] += u;
        __syncthreads();
    }
    if (t < 256) {
        int excl = sc[t] - d;
        float dv = rsqrtf((float)(d + 1));
        disL[t] = dv;
        int n = (b << 8) + t;
        if (n < NN) {
            dis[n] = dv;
            offs[n] = s + excl;
            if (n == NN - 1) offs[NN] = e;
        }
        lcur[t] = excl;
    }
    __syncthreads();
    for (int j = t; j < cnt; j += 512) {
        unsigned int rec = stage[j];
        int slot = atomicAdd(&lcur[rec & 255u], 1);
        records[s + slot] = rec >> 8;  // now plain src row id
    }
    // epilogue: scale xwsh rows of this bucket by dis (coalesced u32 r/w)
    int n0 = b << 8;
    for (int idx = t; idx < 256 * 16; idx += 512) {   // 16 u32 per row
        int loc = idx >> 4;
        int n = n0 + loc;
        if (n >= NN) break;
        uint_t* p = (uint_t*)(xwsh + ((size_t)n << 5)) + (idx & 15);
        uint_t v = *p;
        float dv = disL[loc];
        float lo = h2f((ushort_t)(v & 0xffffu)) * dv;
        float hi = h2f((ushort_t)(v >> 16)) * dv;
        *p = (uint_t)f2h_u(lo) | ((uint_t)f2h_u(hi) << 16);
    }
}

// ===========================================================================
// k5: aggregate, zero-reduce layout. Half-wave (32 lanes) = one node; lane
// owns one output dim and serially walks the node's edge list. Per edge the
// 32 lanes read one coalesced 64B row (u16/lane); f32 accumulate; unroll 8
// keeps 8 gathers in flight. No cross-lane reduction at all.
// ===========================================================================
__global__ __launch_bounds__(256)
void aggregate_kernel(const int* __restrict__ offs, const int* __restrict__ srcs,
                      const float* __restrict__ dis, const ushort_t* __restrict__ xwsh,
                      const float* __restrict__ bias, float* __restrict__ out) {
    int gw = (int)((blockIdx.x * (long long)blockDim.x + threadIdx.x) >> 6);
    int half = (threadIdx.x >> 5) & 1;
    int wid = gw * 2 + half;
    if (wid >= NN) return;
    int d = threadIdx.x & 31;

    int s = offs[wid], e = offs[wid + 1];
    float acc = h2f(xwsh[((size_t)wid << 5) + d]);   // self-loop
    int i = s;
    for (; i + 8 <= e; i += 8) {
        int r0 = srcs[i + 0], r1 = srcs[i + 1], r2 = srcs[i + 2], r3 = srcs[i + 3];
        int r4 = srcs[i + 4], r5 = srcs[i + 5], r6 = srcs[i + 6], r7 = srcs[i + 7];
        ushort_t u0 = xwsh[((size_t)r0 << 5) + d];
        ushort_t u1 = xwsh[((size_t)r1 << 5) + d];
        ushort_t u2 = xwsh[((size_t)r2 << 5) + d];
        ushort_t u3 = xwsh[((size_t)r3 << 5) + d];
        ushort_t u4 = xwsh[((size_t)r4 << 5) + d];
        ushort_t u5 = xwsh[((size_t)r5 << 5) + d];
        ushort_t u6 = xwsh[((size_t)r6 << 5) + d];
        ushort_t u7 = xwsh[((size_t)r7 << 5) + d];
        acc += h2f(u0); acc += h2f(u1); acc += h2f(u2); acc += h2f(u3);
        acc += h2f(u4); acc += h2f(u5); acc += h2f(u6); acc += h2f(u7);
    }
    if (i + 4 <= e) {
        int r0 = srcs[i + 0], r1 = srcs[i + 1], r2 = srcs[i + 2], r3 = srcs[i + 3];
        ushort_t u0 = xwsh[((size_t)r0 << 5) + d];
        ushort_t u1 = xwsh[((size_t)r1 << 5) + d];
        ushort_t u2 = xwsh[((size_t)r2 << 5) + d];
        ushort_t u3 = xwsh[((size_t)r3 << 5) + d];
        acc += h2f(u0); acc += h2f(u1); acc += h2f(u2); acc += h2f(u3);
        i += 4;
    }
    for (; i < e; ++i) acc += h2f(xwsh[((size_t)srcs[i] << 5) + d]);

    out[((size_t)wid << 5) + d] = dis[wid] * acc + bias[d];
}

// ===========================================================================
// Fallback path (R1) if workspace is too small
// ===========================================================================
__global__ void deg_count_kernel(const int* __restrict__ col, int* __restrict__ deg) {
    int e = blockIdx.x * blockDim.x + threadIdx.x;
    if (e < NE) atomicAdd(&deg[col[e]], 1);
}
__global__ void dis_kernel(const int* __restrict__ deg, float* __restrict__ dis) {
    int i = blockIdx.x * blockDim.x + threadIdx.x;
    if (i < NN) dis[i] = rsqrtf((float)(deg[i] + 1));
}
__global__ void xw_init_kernel(const float* __restrict__ x, const float* __restrict__ W,
                               const float* __restrict__ b, const float* __restrict__ dis,
                               float* __restrict__ xw, float* __restrict__ out) {
    __shared__ float Ws[DIN * DOUT];
    for (int i = threadIdx.x; i < DIN * DOUT; i += blockDim.x) Ws[i] = W[i];
    __syncthreads();
    int idx = blockIdx.x * blockDim.x + threadIdx.x;
    if (idx >= NN * DOUT) return;
    int n = idx >> 5;
    int d = idx & (DOUT - 1);
    const float* xr = x + (long long)n * DIN;
    float acc = 0.f;
#pragma unroll
    for (int k = 0; k < DIN; ++k) acc += xr[k] * Ws[k * DOUT + d];
    xw[idx] = acc;
    float di = dis[n];
    out[idx] = di * di * acc + b[d];
}
__global__ void scatter_kernel(const int* __restrict__ row, const int* __restrict__ col,
                               const float* __restrict__ dis, const float* __restrict__ xw,
                               float* __restrict__ out) {
    long long idx = (long long)blockIdx.x * blockDim.x + threadIdx.x;
    if (idx >= (long long)NE * DOUT) return;
    int e = (int)(idx >> 5);
    int d = (int)(idx & (DOUT - 1));
    int r = row[e];
    int c = col[e];
    atomicAdd(&out[c * DOUT + d], dis[r] * dis[c] * xw[r * DOUT + d]);
}

// ===========================================================================
extern "C" void kernel_launch(void* const* d_in, const int* in_sizes, int n_in,
                              void* d_out, int out_size, void* d_ws, size_t ws_size,
                              hipStream_t stream) {
    const float* x  = (const float*)d_in[0];
    const int*   ei = (const int*)d_in[1];
    const float* W  = (const float*)d_in[2];
    const float* b  = (const float*)d_in[3];
    float* out = (float*)d_out;

    const int* row = ei;       // edge_index[0] = source
    const int* col = ei + NE;  // edge_index[1] = target

    char* ws = (char*)d_ws;
    int*          histmat = (int*)(ws + 0);          //   800,768 B (512*391*4)
    int*          bsum    = (int*)(ws + 800768);     //     1,564 B
    int*          base    = (int*)(ws + 802432);     //     1,568 B (NBUK+1)
    int*          offs    = (int*)(ws + 804096);     //   400,004 B (NN+1)
    float*        dis     = (float*)(ws + 1204224);  //   400,000 B
    unsigned int* records = (unsigned int*)(ws + 1604352);  // 6,400,000 B
    ushort_t*     xwsh    = (ushort_t*)(ws + 8004352);      // 6,400,000 B
    ushort_t*     Wht     = (ushort_t*)(ws + 14404352);     //     8,192 B
    const size_t WS_NEEDED = 14412544ull;

    if (ws_size >= WS_NEEDED) {
        hist_kernel<<<FILLB, 256, 0, stream>>>(col, histmat);
        colscan_kernel<<<NBUK, 512, 0, stream>>>(histmat, bsum);
        bscan_wb_kernel<<<9, 512, 0, stream>>>(bsum, base, W, Wht);
        fill_xw_kernel<<<FILLB + XWB, 256, 0, stream>>>(row, col, base, histmat,
                                                        records, x, Wht, xwsh);
        sort_kernel<<<NBUK, 512, 0, stream>>>(base, records, dis, offs, xwsh);
        {
            long long waves = (NN + 1) / 2;             // 2 nodes per wave
            int bl = (int)((waves + 3) / 4);            // 4 waves per block
            aggregate_kernel<<<bl, 256, 0, stream>>>(offs, (const int*)records, dis, xwsh, b, out);
        }
    } else {
        // fallback: atomic scatter path
        int* deg = (int*)(ws + 0);
        float* dis2 = (float*)(ws + 400128);
        float* xw = (float*)(ws + 800256);
        hipMemsetAsync(deg, 0, NN * sizeof(int), stream);
        {
            int th = 256, bl = (NE + th - 1) / th;
            deg_count_kernel<<<bl, th, 0, stream>>>(col, deg);
        }
        {
            int th = 256, bl = (NN + th - 1) / th;
            dis_kernel<<<bl, th, 0, stream>>>(deg, dis2);
        }
        {
            long long total = (long long)NN * DOUT;
            int bl = (int)((total + 255) / 256);
            xw_init_kernel<<<bl, 256, 0, stream>>>(x, W, b, dis2, xw, out);
        }
        {
            long long total = (long long)NE * DOUT;
            int bl = (int)((total + 255) / 256);
            scatter_kernel<<<bl, 256, 0, stream>>>(row, col, dis2, xw, out);
        }
    }
}